// Round 12
// baseline (2584.070 us; speedup 1.0000x reference)
//
#include <hip/hip_runtime.h>
#include <hip/hip_bf16.h>
#include <cstdint>
#include <cstddef>

#define HID 512
#define N_INT 131072
#define N_INIT 32768
#define WT1 ((size_t)HID * HID)

typedef __attribute__((ext_vector_type(8))) short short8_t;
typedef __attribute__((ext_vector_type(4))) short short4_t;
typedef __attribute__((ext_vector_type(4))) float floatx4;

__device__ __forceinline__ float bf2f(unsigned short u) {
  return __uint_as_float(((unsigned)u) << 16);
}
__device__ __forceinline__ unsigned short f2bf_rne(float x) {
  unsigned u = __float_as_uint(x);
  unsigned r = u + 0x7FFF + ((u >> 16) & 1);
  return (unsigned short)(r >> 16);
}
__device__ __forceinline__ void st_split(unsigned short* hi, unsigned short* lo,
                                         size_t off, float x) {
  unsigned short h = f2bf_rne(x);
  hi[off] = h;
  lo[off] = f2bf_rne(x - bf2f(h));
}

// LDS activation plane layout: [16 rows][1024 ushorts: hi 0..511 | lo 512..1023],
// 16B slot index XOR-swizzled with (row&7). aoff preserves uscol&7, so any
// write/read within one 8-ushort slot stays contiguous.
__device__ __forceinline__ int aoff(int row, int uscol) {
  return (row << 10) + ((((uscol >> 3) ^ (row & 7)) << 3) | (uscol & 7));
}

// ---------------------------------------------------------------------------
// W split + pack into B-fraglet layout (same as prior verified rounds):
//   fraglet (n>>4, k>>5); lane = ((k>>3)&3)*16 + (n&15); elem = k&7.
// ---------------------------------------------------------------------------
__global__ __launch_bounds__(512) void wsplit(
    const float* __restrict__ W,
    unsigned short* __restrict__ WfH, unsigned short* __restrict__ WfL)
{
  int n = blockIdx.x;
  int k = threadIdx.x;
  float w = W[(size_t)k * HID + n];
  size_t o = ((((size_t)(n >> 4) * 16 + (k >> 5)) * 64
               + ((k >> 3) & 3) * 16 + (n & 15)) << 3) + (k & 7);
  st_split(WfH, WfL, o, w);
}

// ---------------------------------------------------------------------------
// Fully fused MLP pass, SWAPPED-OPERAND MFMA version.
// mfma(W_frag, Act_frag): output has lane&15 = m-row, reg j = consecutive n.
// -> inter-layer epilogue writes are aligned 8B ds_write_b64 (4 consecutive
// next-layer-k bf16 per store) instead of 160 scalar u16 scatters per lane.
// Product terms (Wh*Ah, Wl*Ah, Wh*Al) identical & same accumulation order as
// rounds 2-11 -> bit-identical numerics.
// Block = 16 rows x 512 cols, 512 thr (8 waves, each owns a 64-col slice).
// ---------------------------------------------------------------------------
template <int NS>
__global__ __launch_bounds__(512) void fused_mlp(
    const float* __restrict__ xt,
    const float* __restrict__ W0, const float* __restrict__ b0,
    const unsigned short* __restrict__ Wf,   // 6 planes: L1H,L1L,L2H,L2L,L3H,L3L
    const float* __restrict__ b1, const float* __restrict__ b2,
    const float* __restrict__ b3,
    const float* __restrict__ W4, const float* __restrict__ b4,
    const float* __restrict__ cc,            // c (interior), unused for init
    const float* __restrict__ t0,            // f (interior) or g (init)
    const float* __restrict__ t1,            // unused or gd (init)
    float* __restrict__ out, float scale)
{
  __shared__ unsigned short Ald[NS][16][1024];  // NS=5 -> 160 KiB, NS=2 -> 64 KiB

  const int tid = threadIdx.x;
  const long rowbase = (long)blockIdx.x * 16;

  // ---- layer 0: closed-form tangents straight into LDS ----
  {
    const int row = tid & 15;
    const int cg = tid >> 4;  // 0..31, 16 cols each
    const long gr = rowbase + row;
    const float x = xt[gr * 2 + 0];
    const float tv = xt[gr * 2 + 1];
#pragma unroll
    for (int sc = 0; sc < 2; ++sc) {
      const int j0 = cg * 16 + sc * 8;
      short8_t h[NS], l[NS];
#pragma unroll
      for (int jj = 0; jj < 8; ++jj) {
        const float wx = W0[j0 + jj];
        const float wt = W0[HID + j0 + jj];
        const float a = fmaf(x, wx, fmaf(tv, wt, b0[j0 + jj]));
        const float y = tanhf(a);
        const float d = 1.f - y * y;
        const float vals[5] = {y, d * wt, -2.f * y * d * wt * wt,
                               d * wx, -2.f * y * d * wx * wx};
#pragma unroll
        for (int p = 0; p < NS; ++p) {
          const unsigned short hv = f2bf_rne(vals[p]);
          h[p][jj] = (short)hv;
          l[p][jj] = (short)f2bf_rne(vals[p] - bf2f(hv));
        }
      }
#pragma unroll
      for (int p = 0; p < NS; ++p) {
        *(short8_t*)&Ald[p][0][aoff(row, j0)] = h[p];
        *(short8_t*)&Ald[p][0][aoff(row, 512 + j0)] = l[p];
      }
    }
  }
  __syncthreads();

  // ---- 3 hidden GEMM layers ----
  const int lane = tid & 63;
  const int wv = tid >> 6;        // 0..7: 64-col slice
  const int row = lane & 15;      // operand row (m for act, n for W)
  const int kq = lane >> 4;       // k-quarter
  const int rx = row & 7;
  const int rbase = row << 10;

  for (int L = 0; L < 3; ++L) {
    const unsigned short* __restrict__ WH = Wf + (size_t)L * 2 * WT1;
    const unsigned short* __restrict__ WL2 = WH + WT1;

    floatx4 acc[NS][4];
#pragma unroll
    for (int s = 0; s < NS; ++s)
#pragma unroll
      for (int cf = 0; cf < 4; ++cf)
#pragma unroll
        for (int e = 0; e < 4; ++e) acc[s][cf][e] = 0.f;

#pragma unroll 4
    for (int t = 0; t < 16; ++t) {
      short8_t ah[NS], al[NS], bhv[4], blv[4];
#pragma unroll
      for (int s = 0; s < NS; ++s) {
        ah[s] = *(const short8_t*)&Ald[s][0][rbase + ((((t << 2) + kq) ^ rx) << 3)];
        al[s] = *(const short8_t*)&Ald[s][0][rbase + (((64 + (t << 2) + kq) ^ rx) << 3)];
      }
#pragma unroll
      for (int cf = 0; cf < 4; ++cf) {
        const size_t bo = (((size_t)((wv * 4 + cf) * 16 + t)) << 9) + (lane << 3);
        bhv[cf] = *(const short8_t*)(WH + bo);
        blv[cf] = *(const short8_t*)(WL2 + bo);
      }
      // swapped operands: first arg = W, second = act -> D[n][m] transposed
#pragma unroll
      for (int s = 0; s < NS; ++s)
#pragma unroll
        for (int cf = 0; cf < 4; ++cf) {
          acc[s][cf] = __builtin_amdgcn_mfma_f32_16x16x32_bf16(bhv[cf], ah[s], acc[s][cf], 0, 0, 0);
          acc[s][cf] = __builtin_amdgcn_mfma_f32_16x16x32_bf16(blv[cf], ah[s], acc[s][cf], 0, 0, 0);
          acc[s][cf] = __builtin_amdgcn_mfma_f32_16x16x32_bf16(bhv[cf], al[s], acc[s][cf], 0, 0, 0);
        }
    }
    __syncthreads();  // all waves done reading this layer's activations

    // In swapped layout: this lane's 16 outputs are for m-row = `row`,
    // n = wv*64 + cf*16 + kq*4 + j  (4 consecutive n per cf).
    if (L < 2) {
      const float* __restrict__ bias = (L == 0) ? b1 : b2;
#pragma unroll
      for (int cf = 0; cf < 4; ++cf) {
        const int n = (wv << 6) + (cf << 4) + (kq << 2);
        const float4 bv4 = *(const float4*)(bias + n);
        const float bvv[4] = {bv4.x, bv4.y, bv4.z, bv4.w};
        short4_t h[NS], l[NS];
#pragma unroll
        for (int j = 0; j < 4; ++j) {
          const float a0 = acc[0][cf][j] + bvv[j];
          const float e = __expf(2.f * a0);
          const float y = 1.f - __fdividef(2.f, e + 1.f);
          const float d = 1.f - y * y;
          const float a1 = acc[1][cf][j];
          const float o1 = d * a1;
          float vals[5];
          vals[0] = y;
          vals[1] = o1;
          if (NS == 5) {
            const float a2 = acc[2][cf][j];
            const float a3 = acc[3][cf][j];
            const float a4 = acc[4][cf][j];
            vals[2] = fmaf(-2.f * y * a1, o1, d * a2);
            vals[3] = d * a3;
            vals[4] = fmaf(-2.f * y * vals[3], a3, d * a4);
          }
#pragma unroll
          for (int p = 0; p < NS; ++p) {
            const unsigned short hv = f2bf_rne(vals[p]);
            h[p][j] = (short)hv;
            l[p][j] = (short)f2bf_rne(vals[p] - bf2f(hv));
          }
        }
#pragma unroll
        for (int p = 0; p < NS; ++p) {
          *(short4_t*)&Ald[p][0][aoff(row, n)] = h[p];
          *(short4_t*)&Ald[p][0][aoff(row, 512 + n)] = l[p];
        }
      }
      __syncthreads();
    } else {
      // ---- final layer: coupling + 512->1 dot + loss ----
      float s0 = 0.f, s1 = 0.f;
#pragma unroll
      for (int cf = 0; cf < 4; ++cf) {
        const int n = (wv << 6) + (cf << 4) + (kq << 2);
        const float4 bv4 = *(const float4*)(b3 + n);
        const float4 w44 = *(const float4*)(W4 + n);
        const float bvv[4] = {bv4.x, bv4.y, bv4.z, bv4.w};
        const float wvv[4] = {w44.x, w44.y, w44.z, w44.w};
#pragma unroll
        for (int j = 0; j < 4; ++j) {
          const float a0 = acc[0][cf][j] + bvv[j];
          const float e = __expf(2.f * a0);
          const float y = 1.f - __fdividef(2.f, e + 1.f);
          const float d = 1.f - y * y;
          const float a1 = acc[1][cf][j];
          const float o1 = d * a1;
          if (NS == 5) {
            const float a2 = acc[2][cf][j];
            const float a3 = acc[3][cf][j];
            const float a4 = acc[4][cf][j];
            const float o2 = fmaf(-2.f * y * a1, o1, d * a2);
            const float o3 = d * a3;
            const float o4 = fmaf(-2.f * y * o3, a3, d * a4);
            s0 = fmaf(o2, wvv[j], s0);   // u_tt partial for m-row `row`
            s1 = fmaf(o4, wvv[j], s1);   // u_xx partial
          } else {
            s0 = fmaf(y, wvv[j], s0);    // u partial
            s1 = fmaf(o1, wvv[j], s1);   // u_t partial
          }
        }
      }
      // reduce over the 4 kq-groups (lanes sharing m-row): flip bits 4,5
      s0 += __shfl_xor(s0, 16); s0 += __shfl_xor(s0, 32);
      s1 += __shfl_xor(s1, 16); s1 += __shfl_xor(s1, 32);
      // cross-wave reduce via LDS scratch (activations no longer needed)
      float* scr = (float*)&Ald[0][0][0];  // [2][8][16]
      if (lane < 16) {
        scr[(wv << 4) + lane] = s0;
        scr[128 + (wv << 4) + lane] = s1;
      }
      __syncthreads();
      if (tid < 16) {
        float q0 = 0.f, q1 = 0.f;
#pragma unroll
        for (int w = 0; w < 8; ++w) {
          q0 += scr[(w << 4) + tid];
          q1 += scr[128 + (w << 4) + tid];
        }
        if (NS == 5) {
          const float c0 = cc[0];
          const float pred = q0 - c0 * c0 * q1;
          const float r = pred - t0[rowbase + tid];
          float v = r * r;
#pragma unroll
          for (int off = 1; off < 16; off <<= 1) v += __shfl_xor(v, off);
          if (tid == 0) atomicAdd(out + 2, scale * v);
        } else {
          const float r0 = q0 + b4[0] - t0[rowbase + tid];
          const float r1 = q1 - t1[rowbase + tid];
          float v0 = r0 * r0, v1 = r1 * r1;
#pragma unroll
          for (int off = 1; off < 16; off <<= 1) {
            v0 += __shfl_xor(v0, off);
            v1 += __shfl_xor(v1, off);
          }
          if (tid == 0) {
            atomicAdd(out + 0, scale * v0);
            atomicAdd(out + 1, scale * v1);
          }
        }
      }
    }
  }
}

// ---------------------------------------------------------------------------
extern "C" void kernel_launch(void* const* d_in, const int* in_sizes, int n_in,
                              void* d_out, int out_size, void* d_ws, size_t ws_size,
                              hipStream_t stream)
{
  const float* xt_int  = (const float*)d_in[0];
  const float* f       = (const float*)d_in[1];
  const float* xt_init = (const float*)d_in[2];
  const float* g       = (const float*)d_in[3];
  const float* gd      = (const float*)d_in[4];
  const float* W0 = (const float*)d_in[5];
  const float* b0 = (const float*)d_in[6];
  const float* W1 = (const float*)d_in[7];
  const float* b1 = (const float*)d_in[8];
  const float* W2 = (const float*)d_in[9];
  const float* b2 = (const float*)d_in[10];
  const float* W3 = (const float*)d_in[11];
  const float* b3 = (const float*)d_in[12];
  const float* W4 = (const float*)d_in[13];
  const float* b4 = (const float*)d_in[14];
  const float* c  = (const float*)d_in[15];
  float* out = (float*)d_out;

  hipMemsetAsync(out, 0, 3 * sizeof(float), stream);

  unsigned short* Wt = (unsigned short*)d_ws;  // 6 planes = 3 MiB of ws

  wsplit<<<HID, HID, 0, stream>>>(W1, Wt + 0 * WT1, Wt + 1 * WT1);
  wsplit<<<HID, HID, 0, stream>>>(W2, Wt + 2 * WT1, Wt + 3 * WT1);
  wsplit<<<HID, HID, 0, stream>>>(W3, Wt + 4 * WT1, Wt + 5 * WT1);

  const float sc_f = 0.5f / (float)N_INT;
  const float sc_i = 0.5f / (float)N_INIT;

  fused_mlp<5><<<N_INT / 16, 512, 0, stream>>>(
      xt_int, W0, b0, Wt, b1, b2, b3, W4, b4, c, f, nullptr, out, sc_f);
  fused_mlp<2><<<N_INIT / 16, 512, 0, stream>>>(
      xt_init, W0, b0, Wt, b1, b2, b3, W4, b4, nullptr, g, gd, out, sc_i);
}